// Round 13
// baseline (56.257 us; speedup 1.0000x reference)
//
#include <hip/hip_runtime.h>

// HMLoss: 4-region histogram-matching L1 loss, H=W=2048 — single fused kernel.
// WAVE-SPLIT balanced blocks: every block is identical; threads [0,512) (8
// waves) build the src fine histogram from fake+mask_A (key = trunc(v)+
// cdfbin(v) in [0,512), packed u64 (N<<41 | S), S = v in 2^11 fixed point),
// threads [512,1024) build the tar cdf histograms from ref_B+mask_B (+ the
// faithful (mask_A==11) bug term) into 2 LDS replicas (4 waves each).
// Per-CU work is thus perfectly balanced (no src-vs-tar straggler blocks).
// Loss from per-coarse-bin stats: sum|v-t| = (t<=b) ? S-N*t : N*t-S (exact).
//
// Tail (r10-proven): blocks drain flush atomics (vmcnt) and bump a ticket;
// blocks >=12 exit; blocks 0..11 spin (acquire+s_sleep) until ticket==512,
// then each computes one (region,channel): division-hoisted bit-faithful
// serial cumsums, binary-search transfer table (== reference's linear scan),
// exact fixed-point loss; combine via atomic acc + second ticket.
//
// ws: [0,393216) u64 gNS[8][12][512]; [393216,491520) u64 gT[8][12][128];
//     [491520) u32 ticket; [491524) u32 ticket2; [491528) u64 acc.

typedef unsigned long long u64;
typedef long long s64;

#define M41 ((1ull << 41) - 1)

#define KEEPF4(v) asm volatile("" :: "v"((v).x), "v"((v).y), "v"((v).z), "v"((v).w))
#define KEEPI4(v) asm volatile("" :: "v"((v).x), "v"((v).y), "v"((v).z), "v"((v).w))

// 3-bit region code per label: 0=none,1=face,2=hair,3=eyeL,4=eyeR
static constexpr u64 REGA =
    (1ull << (3 * 1)) | (3ull << (3 * 2)) | (4ull << (3 * 3)) |
    (3ull << (3 * 4)) | (4ull << (3 * 5)) | (1ull << (3 * 7)) |
    (1ull << (3 * 8)) | (1ull << (3 * 10)) | (1ull << (3 * 11)) |
    (1ull << (3 * 14)) | (2ull << (3 * 17));
static constexpr u64 REGB =   // face set lacks 11 (reference keeps the bug)
    (1ull << (3 * 1)) | (3ull << (3 * 2)) | (4ull << (3 * 3)) |
    (3ull << (3 * 4)) | (4ull << (3 * 5)) | (1ull << (3 * 7)) |
    (1ull << (3 * 8)) | (1ull << (3 * 10)) | (1ull << (3 * 14)) |
    (2ull << (3 * 17));

__device__ __forceinline__ float denorm255(float x) {
  float t = (x + 1.0f) * 0.5f;
  t = fminf(fmaxf(t, 0.0f), 1.0f);
  return t * 255.0f;
}

// v >= 0: cast = trunc = floor; only upper clamp needed.
__device__ __forceinline__ int bin_of(float v) {
  int b = (int)(v * (256.0f / 255.0f));
  return b > 255 ? 255 : b;
}

__global__ __launch_bounds__(1024, 8) void hm_kernel(
    const float* __restrict__ fake, const float* __restrict__ refb,
    const int* __restrict__ ma, const int* __restrict__ mb,
    u64* __restrict__ gNS, u64* __restrict__ gT,
    unsigned* __restrict__ ticket, unsigned* __restrict__ ticket2,
    u64* __restrict__ acc, float* __restrict__ out, int npix) {
  // [0,48K): ns[12][512] u64; [48K,72K): th[2][12][256] u32. 72KB total.
  __shared__ u64 lds64[9216];
  const int tid = threadIdx.x;
  const int nq = npix >> 2;

  u64* ns = lds64;                                  // [12][512]
  unsigned* th0 = (unsigned*)(lds64 + 6144);        // [2][3072]

  for (int i = tid; i < 6144; i += 1024) ns[i] = 0ull;
  for (int i = tid; i < 6144; i += 1024) th0[i] = 0u;
  __syncthreads();

  if (tid < 512) {
    // ---------------- src fine histogram (8 waves) ----------------
    const float4* f0p = (const float4*)fake;
    const float4* f1p = (const float4*)(fake + npix);
    const float4* f2p = (const float4*)(fake + 2 * npix);
    const int4* map = (const int4*)ma;

    auto proc = [&](int4 m4, float4 f0, float4 f1, float4 f2) {
      int mm[4] = {m4.x, m4.y, m4.z, m4.w};
      float fa[3][4] = {{f0.x, f0.y, f0.z, f0.w},
                        {f1.x, f1.y, f1.z, f1.w},
                        {f2.x, f2.y, f2.z, f2.w}};
#pragma unroll
      for (int k = 0; k < 4; ++k) {
        unsigned l = (unsigned)mm[k];
        int code = (int)((REGA >> (l + l + l)) & 7u);   // labels are 0..18
        if (code) {
          int base = (code - 1) * 3;                    // sreg*3
#pragma unroll
          for (int c = 0; c < 3; ++c) {
            float v = denorm255(fa[c][k]);
            int key = (int)v + bin_of(v);               // 0..510
            u64 pack = (1ull << 41) | (u64)(unsigned)(v * 2048.0f);
            atomicAdd(&ns[(base + c) * 512 + key], pack);
          }
        }
      }
    };

    // 2 quads/iter; all 8 loads issued, then FORCE-LIVED (no sinking).
    for (int q0 = blockIdx.x * 1024 + tid; q0 < nq; q0 += 512 * 1024) {
      int q1 = q0 + 512;
      bool h1 = q1 < nq;
      int4 mA = map[q0];
      float4 a0 = f0p[q0], a1 = f1p[q0], a2 = f2p[q0];
      int4 mB = mA; float4 b0 = a0, b1 = a1, b2 = a2;
      if (h1) { mB = map[q1]; b0 = f0p[q1]; b1 = f1p[q1]; b2 = f2p[q1]; }
      KEEPI4(mA); KEEPF4(a0); KEEPF4(a1); KEEPF4(a2);
      KEEPI4(mB); KEEPF4(b0); KEEPF4(b1); KEEPF4(b2);
      proc(mA, a0, a1, a2);
      if (h1) proc(mB, b0, b1, b2);
    }
  } else {
    // ---------------- tar cdf histogram (8 waves, 2 replicas) ----------
    unsigned* th = th0 + ((tid >> 8) & 1) * 3072;   // 4 waves per replica
    const int ts = tid - 512;

    const float4* r0p = (const float4*)refb;
    const float4* r1p = (const float4*)(refb + npix);
    const float4* r2p = (const float4*)(refb + 2 * npix);
    const int4* map = (const int4*)ma;
    const int4* mbp = (const int4*)mb;

    for (int q = blockIdx.x * 1024 + 512 + ts; q < nq; q += 512 * 1024) {
      int4 ma4 = map[q], mb4 = mbp[q];
      float4 r0 = r0p[q], r1 = r1p[q], r2 = r2p[q];
      KEEPI4(ma4); KEEPI4(mb4); KEEPF4(r0); KEEPF4(r1); KEEPF4(r2);
      int mm[4] = {ma4.x, ma4.y, ma4.z, ma4.w};
      int bb[4] = {mb4.x, mb4.y, mb4.z, mb4.w};
      float rr[3][4] = {{r0.x, r0.y, r0.z, r0.w},
                        {r1.x, r1.y, r1.z, r1.w},
                        {r2.x, r2.y, r2.z, r2.w}};
#pragma unroll
      for (int k = 0; k < 4; ++k) {
        unsigned l = (unsigned)bb[k];
        int code = (int)((REGB >> (l + l + l)) & 7u);
        int fval = (code == 1 ? 1 : 0) + (mm[k] == 11 ? 1 : 0);
        if (fval > 0) {
          float fs = (float)fval;
#pragma unroll
          for (int c = 0; c < 3; ++c)
            atomicAdd(&th[c * 256 + bin_of(denorm255(rr[c][k]) * fs)], 1u);
        }
        if (code >= 2) {
          int base = (code - 1) * 3;                    // treg*3
#pragma unroll
          for (int c = 0; c < 3; ++c)
            atomicAdd(&th[(base + c) * 256 + bin_of(denorm255(rr[c][k]))], 1u);
        }
      }
    }
  }
  __syncthreads();

  // merge tar replicas
  for (int i = tid; i < 3072; i += 1024) th0[i] += th0[i + 3072];
  __syncthreads();

  // flush both tables: 8 copies, rotated start
  {
    int copy = blockIdx.x & 7;
    int rot = ((blockIdx.x >> 3) & 63) * 8;
    for (int i = tid; i < 6144; i += 1024) {
      int rc = i >> 9, key = ((i & 511) + rot) & 511;   // 512 = pow2: ok
      u64 v = ns[rc * 512 + key];
      if (v) atomicAdd(&gNS[copy * 6144 + rc * 512 + key], v);
    }
    for (int i = tid; i < 1536; i += 1024) {
      int rc = i >> 7, p = ((i & 127) + rot) & 127;     // 128 = pow2: ok
      u64 w = (u64)th0[rc * 256 + 2 * p] | ((u64)th0[rc * 256 + 2 * p + 1] << 32);
      if (w) atomicAdd(&gT[copy * 1536 + rc * 128 + p], w);
    }
  }

  // Drain flush atomics (acked at coherence point), block-order, bump ticket.
  // No __threadfence (buffer_wbl2 L2 walk = round-8's 5x regression).
  asm volatile("s_waitcnt vmcnt(0)" ::: "memory");
  __syncthreads();
  if (tid == 0) atomicAdd(ticket, 1u);
  if (blockIdx.x >= 12) return;

  // ---------------- 12-block parallel tail ----------------
  if (tid == 0) {
    while (__hip_atomic_load(ticket, __ATOMIC_ACQUIRE,
                             __HIP_MEMORY_SCOPE_AGENT) < 512u)
      __builtin_amdgcn_s_sleep(8);
  }
  __syncthreads();

  const int rc = blockIdx.x;   // 0..11 = (region*3 + channel)
  u64* Sf = lds64;                               // [512]
  unsigned* Nf = (unsigned*)(lds64 + 512);       // [512]
  unsigned* thA = Nf + 512;                      // [256]
  float* qD = (float*)(thA + 256);               // [256]
  float* qA = qD + 256;                          // [256]
  float* dcdf = qA + 256;                        // [256]
  float* acdf = dcdf + 256;                      // [256]
  unsigned* rsum = (unsigned*)(acdf + 256);      // [512]
  s64* red = (s64*)(rsum + 512);                 // [256]

  unsigned hD = 0, wA = 0;
  if (tid < 256) {
    u64 a0 = 0, a1 = 0, w = 0;
#pragma unroll
    for (int cp = 0; cp < 8; ++cp) {
      a0 += __hip_atomic_load(&gNS[cp * 6144 + rc * 512 + 2 * tid],
                              __ATOMIC_RELAXED, __HIP_MEMORY_SCOPE_AGENT);
      a1 += __hip_atomic_load(&gNS[cp * 6144 + rc * 512 + 2 * tid + 1],
                              __ATOMIC_RELAXED, __HIP_MEMORY_SCOPE_AGENT);
    }
    if (tid < 128) {
#pragma unroll
      for (int cp = 0; cp < 8; ++cp)
        w += __hip_atomic_load(&gT[cp * 1536 + rc * 128 + tid],
                               __ATOMIC_RELAXED, __HIP_MEMORY_SCOPE_AGENT);
    }
    Nf[2 * tid] = (unsigned)(a0 >> 41); Sf[2 * tid] = a0 & M41;
    Nf[2 * tid + 1] = (unsigned)(a1 >> 41); Sf[2 * tid + 1] = a1 & M41;
    if (tid < 128) {
      thA[2 * tid] = (unsigned)w;
      thA[2 * tid + 1] = (unsigned)(w >> 32);
    }
  }
  __syncthreads();

  if (tid < 256) {
    hD = Nf[2 * tid] + (tid ? Nf[2 * tid - 1] : 0u);  // coarse dst bin count
    wA = thA[tid];
    rsum[tid] = hD;
    rsum[256 + tid] = wA;
  }
  __syncthreads();
  for (int off = 128; off > 0; off >>= 1) {
    if (tid < off) {
      rsum[tid] += rsum[tid + off];
      rsum[256 + tid] += rsum[256 + tid + off];
    }
    __syncthreads();
  }

  // Hoisted divisions: parallel q[b]=h[b]/s is bitwise what the reference's
  // serial loop divides; the serial chain below adds them in identical order.
  if (tid < 256) {
    float sD = fmaxf((float)rsum[0], 1.0f);
    float sA = fmaxf((float)rsum[256], 1.0f);
    qD[tid] = (float)hD / sD;
    qA[tid] = (float)wA / sA;
  }
  __syncthreads();

  if (tid == 0) {          // wave A: bit-faithful serial dst cumsum
    float run = 0.0f;
    for (int b = 0; b < 256; ++b) { run += qD[b]; dcdf[b] = run; }
  }
  if (tid == 64) {         // wave B: tar cumsum, concurrent with wave A
    float run = 0.0f;
    for (int b = 0; b < 256; ++b) { run += qA[b]; acdf[b] = run; }
  }
  __syncthreads();

  if (tid < 256) {
    int t = tid, tb;
    if (t == 0) tb = 0;
    else if (t == 255) tb = 255;
    else {
      // binary search: minimal j in [1,255] with acdf[j] >= di.
      // == reference's first-j linear scan: minimality gives acdf[j-1] < di
      // for j>=2; j==1 additionally needs acdf[0] <= di; else table = t.
      float di = dcdf[t];
      int lo = 1, hi = 255;
      while (lo < hi) {
        int mid = (lo + hi) >> 1;
        if (acdf[mid] >= di) hi = mid; else lo = mid + 1;
      }
      tb = (acdf[lo] >= di && (lo >= 2 || acdf[0] <= di)) ? lo : t;
    }
    // exact loss contribution for coarse bin b = t (2^11 fixed point)
    unsigned Nb = Nf[2 * t] + Nf[2 * t + 1];
    u64 Sb = Sf[2 * t] + Sf[2 * t + 1];
    s64 nt = (s64)Nb * ((s64)tb << 11);
    red[t] = (tb <= t) ? ((s64)Sb - nt) : (nt - (s64)Sb);
  }
  __syncthreads();
  for (int off = 128; off > 0; off >>= 1) {
    if (tid < off) red[tid] += red[tid + off];
    __syncthreads();
  }

  if (tid == 0) {
    atomicAdd(acc, (u64)red[0]);
    asm volatile("s_waitcnt vmcnt(0)" ::: "memory");
    unsigned t2 = __hip_atomic_fetch_add(ticket2, 1u, __ATOMIC_ACQ_REL,
                                         __HIP_MEMORY_SCOPE_AGENT);
    if (t2 == 11u) {       // last of the 12 tail blocks
      s64 total = (s64)__hip_atomic_load(acc, __ATOMIC_ACQUIRE,
                                         __HIP_MEMORY_SCOPE_AGENT);
      out[0] = (float)(0.1 * (double)total / 2048.0 / (3.0 * (double)npix));
    }
  }
}

extern "C" void kernel_launch(void* const* d_in, const int* in_sizes, int n_in,
                              void* d_out, int out_size, void* d_ws, size_t ws_size,
                              hipStream_t stream) {
  const float* fake = (const float*)d_in[0];
  const float* refb = (const float*)d_in[1];
  const int* ma = (const int*)d_in[2];
  const int* mb = (const int*)d_in[3];
  const int npix = in_sizes[2];  // H*W

  u64* gNS = (u64*)d_ws;                                 // [8][6144] u64
  u64* gT = (u64*)((char*)d_ws + 393216);                // [8][1536] u64
  unsigned* ticket = (unsigned*)((char*)d_ws + 491520);  // u32
  unsigned* ticket2 = (unsigned*)((char*)d_ws + 491524); // u32
  u64* acc = (u64*)((char*)d_ws + 491528);               // u64
  float* out = (float*)d_out;

  hipMemsetAsync(d_ws, 0, 491536, stream);
  // 72 KB LDS, 16 waves/block -> 2 blocks/CU; every block identical (balanced).
  hm_kernel<<<512, 1024, 0, stream>>>(fake, refb, ma, mb, gNS, gT, ticket,
                                      ticket2, acc, out, npix);
}

// Round 14
// 52.836 us; speedup vs baseline: 1.0648x; 1.0648x over previous
//
#include <hip/hip_runtime.h>

// HMLoss: 4-region histogram-matching L1 loss, H=W=2048 — single fused kernel.
// (r12 revert — best verified: 53.2 us, absmax 0. r13's wave-split had a
// coverage bug: tar half only visited (q mod 1024) >= 512. Reverted.)
//
// Split main loop: blocks [0,256) build the src fine histogram (fake+mask_A):
// key = trunc(v)+cdfbin(v) in [0,512), packed u64 (N<<41 | S), S = v in exact
// 2^11 fixed point. Blocks [256,512) build the tar cdf histograms
// (ref_B+mask_B + the faithful (mask_A==11) bug term) in 4 LDS replicas.
// Loss from per-coarse-bin stats: sum|v-t| = (t<=b) ? S-N*t : N*t-S (exact).
// Loads are force-lived via asm volatile("" :: "v"(x)) to defeat IR sinking.
//
// Tail: blocks drain flush atomics (vmcnt) and bump a ticket; blocks >=12
// exit; blocks 0..11 spin (acquire+s_sleep) until ticket==512, then each
// computes one (region,channel): division-hoisted bit-faithful serial
// cumsums, binary-search transfer table (== reference's first-interval linear
// scan), exact fixed-point loss; combine via atomic acc + second ticket.
//
// ws: [0,393216) u64 gNS[8][12][512]; [393216,491520) u64 gT[8][12][128];
//     [491520) u32 ticket; [491524) u32 ticket2; [491528) u64 acc.

typedef unsigned long long u64;
typedef long long s64;

#define NSRC 256
#define M41 ((1ull << 41) - 1)

#define KEEPF4(v) asm volatile("" :: "v"((v).x), "v"((v).y), "v"((v).z), "v"((v).w))
#define KEEPI4(v) asm volatile("" :: "v"((v).x), "v"((v).y), "v"((v).z), "v"((v).w))

// 3-bit region code per label: 0=none,1=face,2=hair,3=eyeL,4=eyeR
static constexpr u64 REGA =
    (1ull << (3 * 1)) | (3ull << (3 * 2)) | (4ull << (3 * 3)) |
    (3ull << (3 * 4)) | (4ull << (3 * 5)) | (1ull << (3 * 7)) |
    (1ull << (3 * 8)) | (1ull << (3 * 10)) | (1ull << (3 * 11)) |
    (1ull << (3 * 14)) | (2ull << (3 * 17));
static constexpr u64 REGB =   // face set lacks 11 (reference keeps the bug)
    (1ull << (3 * 1)) | (3ull << (3 * 2)) | (4ull << (3 * 3)) |
    (3ull << (3 * 4)) | (4ull << (3 * 5)) | (1ull << (3 * 7)) |
    (1ull << (3 * 8)) | (1ull << (3 * 10)) | (1ull << (3 * 14)) |
    (2ull << (3 * 17));

__device__ __forceinline__ float denorm255(float x) {
  float t = (x + 1.0f) * 0.5f;
  t = fminf(fmaxf(t, 0.0f), 1.0f);
  return t * 255.0f;
}

// v >= 0: cast = trunc = floor; only upper clamp needed.
__device__ __forceinline__ int bin_of(float v) {
  int b = (int)(v * (256.0f / 255.0f));
  return b > 255 ? 255 : b;
}

__global__ __launch_bounds__(1024, 8) void hm_kernel(
    const float* __restrict__ fake, const float* __restrict__ refb,
    const int* __restrict__ ma, const int* __restrict__ mb,
    u64* __restrict__ gNS, u64* __restrict__ gT,
    unsigned* __restrict__ ticket, unsigned* __restrict__ ticket2,
    u64* __restrict__ acc, float* __restrict__ out, int npix) {
  __shared__ u64 lds64[6144];     // 49152 B, phase-multiplexed
  const int tid = threadIdx.x;
  const int nq = npix >> 2;

  if (blockIdx.x < NSRC) {
    // ---------------- src fine histogram ----------------
    u64* ns = lds64;                           // [12][512]
    for (int i = tid; i < 6144; i += 1024) ns[i] = 0ull;
    __syncthreads();

    const float4* f0p = (const float4*)fake;
    const float4* f1p = (const float4*)(fake + npix);
    const float4* f2p = (const float4*)(fake + 2 * npix);
    const int4* map = (const int4*)ma;

    auto proc = [&](int4 m4, float4 f0, float4 f1, float4 f2) {
      int mm[4] = {m4.x, m4.y, m4.z, m4.w};
      float fa[3][4] = {{f0.x, f0.y, f0.z, f0.w},
                        {f1.x, f1.y, f1.z, f1.w},
                        {f2.x, f2.y, f2.z, f2.w}};
#pragma unroll
      for (int k = 0; k < 4; ++k) {
        unsigned l = (unsigned)mm[k];
        int code = (int)((REGA >> (l + l + l)) & 7u);   // labels are 0..18
        if (code) {
          int base = (code - 1) * 3;                    // sreg*3
#pragma unroll
          for (int c = 0; c < 3; ++c) {
            float v = denorm255(fa[c][k]);
            int key = (int)v + bin_of(v);               // 0..510
            u64 pack = (1ull << 41) | (u64)(unsigned)(v * 2048.0f);
            atomicAdd(&ns[(base + c) * 512 + key], pack);
          }
        }
      }
    };

    // 2 quads/iter; all 8 loads issued, then FORCE-LIVED (no sinking).
    for (int q0 = blockIdx.x * 2048 + tid; q0 < nq; q0 += NSRC * 2048) {
      int q1 = q0 + 1024;
      bool h1 = q1 < nq;
      int4 mA = map[q0];
      float4 a0 = f0p[q0], a1 = f1p[q0], a2 = f2p[q0];
      int4 mB = mA; float4 b0 = a0, b1 = a1, b2 = a2;
      if (h1) { mB = map[q1]; b0 = f0p[q1]; b1 = f1p[q1]; b2 = f2p[q1]; }
      KEEPI4(mA); KEEPF4(a0); KEEPF4(a1); KEEPF4(a2);
      KEEPI4(mB); KEEPF4(b0); KEEPF4(b1); KEEPF4(b2);
      proc(mA, a0, a1, a2);
      if (h1) proc(mB, b0, b1, b2);
    }
    __syncthreads();

    int copy = blockIdx.x & 7;
    int rot = ((blockIdx.x >> 3) & 63) * 8;
    for (int i = tid; i < 6144; i += 1024) {
      int rc = i >> 9, key = ((i & 511) + rot) & 511;   // 512 = pow2: ok
      u64 v = ns[rc * 512 + key];
      if (v) atomicAdd(&gNS[copy * 6144 + rc * 512 + key], v);
    }
  } else {
    // ---------------- tar cdf histogram ----------------
    unsigned* th0 = (unsigned*)lds64;          // [4][12][256] replicas
    for (int i = tid; i < 12288; i += 1024) th0[i] = 0u;
    __syncthreads();
    unsigned* th = th0 + (tid >> 8) * 3072;    // per-4-wave-group replica

    const float4* r0p = (const float4*)refb;
    const float4* r1p = (const float4*)(refb + npix);
    const float4* r2p = (const float4*)(refb + 2 * npix);
    const int4* map = (const int4*)ma;
    const int4* mbp = (const int4*)mb;

    for (int q = (blockIdx.x - NSRC) * 1024 + tid; q < nq;
         q += (512 - NSRC) * 1024) {
      int4 ma4 = map[q], mb4 = mbp[q];
      float4 r0 = r0p[q], r1 = r1p[q], r2 = r2p[q];
      KEEPI4(ma4); KEEPI4(mb4); KEEPF4(r0); KEEPF4(r1); KEEPF4(r2);
      int mm[4] = {ma4.x, ma4.y, ma4.z, ma4.w};
      int bb[4] = {mb4.x, mb4.y, mb4.z, mb4.w};
      float rr[3][4] = {{r0.x, r0.y, r0.z, r0.w},
                        {r1.x, r1.y, r1.z, r1.w},
                        {r2.x, r2.y, r2.z, r2.w}};
#pragma unroll
      for (int k = 0; k < 4; ++k) {
        unsigned l = (unsigned)bb[k];
        int code = (int)((REGB >> (l + l + l)) & 7u);
        int fval = (code == 1 ? 1 : 0) + (mm[k] == 11 ? 1 : 0);
        if (fval > 0) {
          float fs = (float)fval;
#pragma unroll
          for (int c = 0; c < 3; ++c)
            atomicAdd(&th[c * 256 + bin_of(denorm255(rr[c][k]) * fs)], 1u);
        }
        if (code >= 2) {
          int base = (code - 1) * 3;                    // treg*3
#pragma unroll
          for (int c = 0; c < 3; ++c)
            atomicAdd(&th[(base + c) * 256 + bin_of(denorm255(rr[c][k]))], 1u);
        }
      }
    }
    __syncthreads();

    // merge 4 replicas
    for (int i = tid; i < 3072; i += 1024)
      th0[i] = th0[i] + th0[i + 3072] + th0[i + 6144] + th0[i + 9216];
    __syncthreads();

    // flush as bin-pairs packed in u64 (no cross-carry: totals < 2^32)
    int copy = blockIdx.x & 7;
    int rot = ((blockIdx.x >> 3) & 63) * 8;
    for (int i = tid; i < 1536; i += 1024) {
      int rc = i >> 7, p = ((i & 127) + rot) & 127;     // 128 = pow2: ok
      u64 w = (u64)th0[rc * 256 + 2 * p] | ((u64)th0[rc * 256 + 2 * p + 1] << 32);
      if (w) atomicAdd(&gT[copy * 1536 + rc * 128 + p], w);
    }
  }

  // Drain flush atomics (acked at coherence point), block-order, bump ticket.
  // No __threadfence (buffer_wbl2 L2 walk = round-8's 5x regression).
  asm volatile("s_waitcnt vmcnt(0)" ::: "memory");
  __syncthreads();
  if (tid == 0) atomicAdd(ticket, 1u);
  if (blockIdx.x >= 12) return;

  // ---------------- 12-block parallel tail ----------------
  if (tid == 0) {
    while (__hip_atomic_load(ticket, __ATOMIC_ACQUIRE,
                             __HIP_MEMORY_SCOPE_AGENT) < 512u)
      __builtin_amdgcn_s_sleep(8);
  }
  __syncthreads();

  const int rc = blockIdx.x;   // 0..11 = (region*3 + channel)
  u64* Sf = lds64;                               // [512]
  unsigned* Nf = (unsigned*)(lds64 + 512);       // [512]
  unsigned* thA = Nf + 512;                      // [256]
  float* qD = (float*)(thA + 256);               // [256]
  float* qA = qD + 256;                          // [256]
  float* dcdf = qA + 256;                        // [256]
  float* acdf = dcdf + 256;                      // [256]
  unsigned* rsum = (unsigned*)(acdf + 256);      // [512]
  s64* red = (s64*)(rsum + 512);                 // [256]

  unsigned hD = 0, wA = 0;
  if (tid < 256) {
    u64 a0 = 0, a1 = 0, w = 0;
#pragma unroll
    for (int cp = 0; cp < 8; ++cp) {
      a0 += __hip_atomic_load(&gNS[cp * 6144 + rc * 512 + 2 * tid],
                              __ATOMIC_RELAXED, __HIP_MEMORY_SCOPE_AGENT);
      a1 += __hip_atomic_load(&gNS[cp * 6144 + rc * 512 + 2 * tid + 1],
                              __ATOMIC_RELAXED, __HIP_MEMORY_SCOPE_AGENT);
    }
    if (tid < 128) {
#pragma unroll
      for (int cp = 0; cp < 8; ++cp)
        w += __hip_atomic_load(&gT[cp * 1536 + rc * 128 + tid],
                               __ATOMIC_RELAXED, __HIP_MEMORY_SCOPE_AGENT);
    }
    Nf[2 * tid] = (unsigned)(a0 >> 41); Sf[2 * tid] = a0 & M41;
    Nf[2 * tid + 1] = (unsigned)(a1 >> 41); Sf[2 * tid + 1] = a1 & M41;
    if (tid < 128) {
      thA[2 * tid] = (unsigned)w;
      thA[2 * tid + 1] = (unsigned)(w >> 32);
    }
  }
  __syncthreads();

  if (tid < 256) {
    hD = Nf[2 * tid] + (tid ? Nf[2 * tid - 1] : 0u);  // coarse dst bin count
    wA = thA[tid];
    rsum[tid] = hD;
    rsum[256 + tid] = wA;
  }
  __syncthreads();
  for (int off = 128; off > 0; off >>= 1) {
    if (tid < off) {
      rsum[tid] += rsum[tid + off];
      rsum[256 + tid] += rsum[256 + tid + off];
    }
    __syncthreads();
  }

  // Hoisted divisions: parallel q[b]=h[b]/s is bitwise what the reference's
  // serial loop divides; the serial chain below adds them in identical order.
  if (tid < 256) {
    float sD = fmaxf((float)rsum[0], 1.0f);
    float sA = fmaxf((float)rsum[256], 1.0f);
    qD[tid] = (float)hD / sD;
    qA[tid] = (float)wA / sA;
  }
  __syncthreads();

  if (tid == 0) {          // wave A: bit-faithful serial dst cumsum
    float run = 0.0f;
    for (int b = 0; b < 256; ++b) { run += qD[b]; dcdf[b] = run; }
  }
  if (tid == 64) {         // wave B: tar cumsum, concurrent with wave A
    float run = 0.0f;
    for (int b = 0; b < 256; ++b) { run += qA[b]; acdf[b] = run; }
  }
  __syncthreads();

  if (tid < 256) {
    int t = tid, tb;
    if (t == 0) tb = 0;
    else if (t == 255) tb = 255;
    else {
      // binary search: minimal j in [1,255] with acdf[j] >= di.
      // == reference's first-j linear scan: minimality gives acdf[j-1] < di
      // for j>=2; j==1 additionally needs acdf[0] <= di; else table = t.
      float di = dcdf[t];
      int lo = 1, hi = 255;
      while (lo < hi) {
        int mid = (lo + hi) >> 1;
        if (acdf[mid] >= di) hi = mid; else lo = mid + 1;
      }
      tb = (acdf[lo] >= di && (lo >= 2 || acdf[0] <= di)) ? lo : t;
    }
    // exact loss contribution for coarse bin b = t (2^11 fixed point)
    unsigned Nb = Nf[2 * t] + Nf[2 * t + 1];
    u64 Sb = Sf[2 * t] + Sf[2 * t + 1];
    s64 nt = (s64)Nb * ((s64)tb << 11);
    red[t] = (tb <= t) ? ((s64)Sb - nt) : (nt - (s64)Sb);
  }
  __syncthreads();
  for (int off = 128; off > 0; off >>= 1) {
    if (tid < off) red[tid] += red[tid + off];
    __syncthreads();
  }

  if (tid == 0) {
    atomicAdd(acc, (u64)red[0]);
    asm volatile("s_waitcnt vmcnt(0)" ::: "memory");
    unsigned t2 = __hip_atomic_fetch_add(ticket2, 1u, __ATOMIC_ACQ_REL,
                                         __HIP_MEMORY_SCOPE_AGENT);
    if (t2 == 11u) {       // last of the 12 tail blocks
      s64 total = (s64)__hip_atomic_load(acc, __ATOMIC_ACQUIRE,
                                         __HIP_MEMORY_SCOPE_AGENT);
      out[0] = (float)(0.1 * (double)total / 2048.0 / (3.0 * (double)npix));
    }
  }
}

extern "C" void kernel_launch(void* const* d_in, const int* in_sizes, int n_in,
                              void* d_out, int out_size, void* d_ws, size_t ws_size,
                              hipStream_t stream) {
  const float* fake = (const float*)d_in[0];
  const float* refb = (const float*)d_in[1];
  const int* ma = (const int*)d_in[2];
  const int* mb = (const int*)d_in[3];
  const int npix = in_sizes[2];  // H*W

  u64* gNS = (u64*)d_ws;                                 // [8][6144] u64
  u64* gT = (u64*)((char*)d_ws + 393216);                // [8][1536] u64
  unsigned* ticket = (unsigned*)((char*)d_ws + 491520);  // u32
  unsigned* ticket2 = (unsigned*)((char*)d_ws + 491524); // u32
  u64* acc = (u64*)((char*)d_ws + 491528);               // u64
  float* out = (float*)d_out;

  hipMemsetAsync(d_ws, 0, 491536, stream);
  // 49.3 KB LDS, 16 waves/block -> 2 blocks/CU; 512 blocks fill the chip.
  hm_kernel<<<512, 1024, 0, stream>>>(fake, refb, ma, mb, gNS, gT, ticket,
                                      ticket2, acc, out, npix);
}